// Round 4
// baseline (165.103 us; speedup 1.0000x reference)
//
#include <hip/hip_runtime.h>
#include <hip/hip_fp16.h>

#define AD 32
#define HID 16
#define IN_DIM 33

typedef float f32x4 __attribute__((ext_vector_type(4)));

union VU {
    f32x4 v;
    __half2 h[4];
};

static inline int imin_host(int a, int b) { return a < b ? a : b; }

__device__ __forceinline__ float sigmoidf_fast(float x) {
    return 1.0f / (1.0f + __expf(-x));
}

// Phase 1: hpre[a][j] = sum_i emb[a][i] * W1[j][i]  (cols 0..31), stored fp16.
__global__ __launch_bounds__(256) void atom_pre_kernel(
    const float* __restrict__ emb,   // [N,32]
    const float* __restrict__ W1,    // [16,33] row-major (out,in)
    __half* __restrict__ hpre,       // [N,16] fp16
    int N)
{
    int a = blockIdx.x * blockDim.x + threadIdx.x;
    if (a >= N) return;

    const f32x4* e4 = reinterpret_cast<const f32x4*>(emb + (size_t)a * AD);
    float x[AD];
#pragma unroll
    for (int q = 0; q < AD / 4; ++q) {
        f32x4 v = e4[q];
        x[4*q+0] = v.x; x[4*q+1] = v.y; x[4*q+2] = v.z; x[4*q+3] = v.w;
    }

    float s[HID];
#pragma unroll
    for (int j = 0; j < HID; ++j) {
        float acc = 0.0f;
#pragma unroll
        for (int i = 0; i < AD; ++i)
            acc = fmaf(x[i], W1[j*IN_DIM + i], acc);
        s[j] = acc;
    }

    VU a0, a1;
#pragma unroll
    for (int q = 0; q < 4; ++q) a0.h[q] = __floats2half2_rn(s[2*q],   s[2*q+1]);
#pragma unroll
    for (int q = 0; q < 4; ++q) a1.h[q] = __floats2half2_rn(s[8+2*q], s[8+2*q+1]);

    f32x4* o4 = reinterpret_cast<f32x4*>(hpre + (size_t)a * HID);
    __builtin_nontemporal_store(a0.v, &o4[0]);
    __builtin_nontemporal_store(a1.v, &o4[1]);
}

// Compute one pair-score given two gathered rows (as 4 f32x4) + energy.
__device__ __forceinline__ float pair_score(
    f32x4 s0, f32x4 s1, f32x4 d0, f32x4 d1,
    float energy, const float* w1c, const float* bb1, const float* w2, float wb2)
{
    VU us0, us1, ud0, ud1;
    us0.v = s0; us1.v = s1; ud0.v = d0; ud1.v = d1;
    float logit = wb2;
#pragma unroll
    for (int q = 0; q < 4; ++q) {
        float2 sf = __half22float2(__hadd2(us0.h[q], ud0.h[q]));
        const int j = 2*q;
        float h0 = sf.x + fmaf(energy, w1c[j],   bb1[j]);
        float h1 = sf.y + fmaf(energy, w1c[j+1], bb1[j+1]);
        logit = fmaf(w2[j],   fmaxf(h0, 0.0f), logit);
        logit = fmaf(w2[j+1], fmaxf(h1, 0.0f), logit);
    }
#pragma unroll
    for (int q = 0; q < 4; ++q) {
        float2 sf = __half22float2(__hadd2(us1.h[q], ud1.h[q]));
        const int j = 8 + 2*q;
        float h0 = sf.x + fmaf(energy, w1c[j],   bb1[j]);
        float h1 = sf.y + fmaf(energy, w1c[j+1], bb1[j+1]);
        logit = fmaf(w2[j],   fmaxf(h0, 0.0f), logit);
        logit = fmaf(w2[j+1], fmaxf(h1, 0.0f), logit);
    }
    return sigmoidf_fast(logit);
}

// Phase 2: TWO outputs per thread (4 edges, 8 row-gathers = 16x16B loads
// all issued before any consumption) to double memory-level parallelism.
__global__ __launch_bounds__(256) void edge_kernel(
    const __half* __restrict__ hpre,   // [N,16] fp16
    const int* __restrict__ eidx,      // [2,E]
    const float* __restrict__ benergy, // [E]
    const float* __restrict__ W1,      // [16,33] (need col 32)
    const float* __restrict__ b1,      // [16]
    const float* __restrict__ W2,      // [16]
    const float* __restrict__ b2,      // [1]
    const float* __restrict__ We,      // [1]
    const float* __restrict__ be,      // [1]
    float* __restrict__ out,           // [half]
    int E, int half)
{
    float w1c[HID], bb1[HID], w2[HID];
#pragma unroll
    for (int j = 0; j < HID; ++j) {
        w1c[j] = W1[j*IN_DIM + 32];
        bb1[j] = b1[j];
        w2[j]  = W2[j];
    }
    const float wb2 = b2[0];
    const float we  = We[0];
    const float bee = be[0];

    const int nt = (half + 1) >> 1;              // threads cover 2 outputs each
    const int t0 = blockIdx.x * blockDim.x + threadIdx.x;
    if (t0 >= nt) return;
    const int t1 = t0 + nt;
    const bool has1 = (t1 < half);
    const int t1s = has1 ? t1 : t0;              // safe substitute

    // 4 edges: (t0, t0+half), (t1, t1+half)
    const int eA0 = t0, eA1 = t0 + half;
    const int eB0 = t1s, eB1 = t1s + half;

    // Stream loads (nontemporal: single-use, keep L2 for the table).
    const int sA0 = __builtin_nontemporal_load(&eidx[eA0]);
    const int dA0 = __builtin_nontemporal_load(&eidx[E + eA0]);
    const int sA1 = __builtin_nontemporal_load(&eidx[eA1]);
    const int dA1 = __builtin_nontemporal_load(&eidx[E + eA1]);
    const int sB0 = __builtin_nontemporal_load(&eidx[eB0]);
    const int dB0 = __builtin_nontemporal_load(&eidx[E + eB0]);
    const int sB1 = __builtin_nontemporal_load(&eidx[eB1]);
    const int dB1 = __builtin_nontemporal_load(&eidx[E + eB1]);
    const float benA0 = __builtin_nontemporal_load(&benergy[eA0]);
    const float benA1 = __builtin_nontemporal_load(&benergy[eA1]);
    const float benB0 = __builtin_nontemporal_load(&benergy[eB0]);
    const float benB1 = __builtin_nontemporal_load(&benergy[eB1]);

    // 8 row gathers x 2 x 16B, all independent.
    const f32x4* pA0s = reinterpret_cast<const f32x4*>(hpre + (size_t)sA0 * HID);
    const f32x4* pA0d = reinterpret_cast<const f32x4*>(hpre + (size_t)dA0 * HID);
    const f32x4* pA1s = reinterpret_cast<const f32x4*>(hpre + (size_t)sA1 * HID);
    const f32x4* pA1d = reinterpret_cast<const f32x4*>(hpre + (size_t)dA1 * HID);
    const f32x4* pB0s = reinterpret_cast<const f32x4*>(hpre + (size_t)sB0 * HID);
    const f32x4* pB0d = reinterpret_cast<const f32x4*>(hpre + (size_t)dB0 * HID);
    const f32x4* pB1s = reinterpret_cast<const f32x4*>(hpre + (size_t)sB1 * HID);
    const f32x4* pB1d = reinterpret_cast<const f32x4*>(hpre + (size_t)dB1 * HID);

    f32x4 gA0s0 = pA0s[0], gA0s1 = pA0s[1];
    f32x4 gA0d0 = pA0d[0], gA0d1 = pA0d[1];
    f32x4 gA1s0 = pA1s[0], gA1s1 = pA1s[1];
    f32x4 gA1d0 = pA1d[0], gA1d1 = pA1d[1];
    f32x4 gB0s0 = pB0s[0], gB0s1 = pB0s[1];
    f32x4 gB0d0 = pB0d[0], gB0d1 = pB0d[1];
    f32x4 gB1s0 = pB1s[0], gB1s1 = pB1s[1];
    f32x4 gB1d0 = pB1d[0], gB1d1 = pB1d[1];

    const float enA0 = fmaf(benA0, we, bee);
    const float enA1 = fmaf(benA1, we, bee);
    const float enB0 = fmaf(benB0, we, bee);
    const float enB1 = fmaf(benB1, we, bee);

    const float scA0 = pair_score(gA0s0, gA0s1, gA0d0, gA0d1, enA0, w1c, bb1, w2, wb2);
    const float scA1 = pair_score(gA1s0, gA1s1, gA1d0, gA1d1, enA1, w1c, bb1, w2, wb2);
    __builtin_nontemporal_store(0.5f * (scA0 + scA1), &out[t0]);

    if (has1) {
        const float scB0 = pair_score(gB0s0, gB0s1, gB0d0, gB0d1, enB0, w1c, bb1, w2, wb2);
        const float scB1 = pair_score(gB1s0, gB1s1, gB1d0, gB1d1, enB1, w1c, bb1, w2, wb2);
        __builtin_nontemporal_store(0.5f * (scB0 + scB1), &out[t1]);
    }
}

// Fallback (workspace too small): fully fused fp32, gathers raw embeddings.
__global__ __launch_bounds__(256) void fused_kernel(
    const float* __restrict__ emb,
    const int* __restrict__ eidx,
    const float* __restrict__ benergy,
    const float* __restrict__ W1, const float* __restrict__ b1,
    const float* __restrict__ W2, const float* __restrict__ b2,
    const float* __restrict__ We, const float* __restrict__ be,
    float* __restrict__ out, int E, int half)
{
    const float we  = We[0];
    const float bee = be[0];
    const float wb2 = b2[0];
    int stride = gridDim.x * blockDim.x;
    for (int t = blockIdx.x * blockDim.x + threadIdx.x; t < half; t += stride) {
        float sc[2];
#pragma unroll
        for (int k = 0; k < 2; ++k) {
            const int e = t + k * half;
            const int src = eidx[e];
            const int dst = eidx[E + e];
            const float4* s4 = reinterpret_cast<const float4*>(emb + (size_t)src * AD);
            const float4* d4 = reinterpret_cast<const float4*>(emb + (size_t)dst * AD);
            float feat[AD];
#pragma unroll
            for (int q = 0; q < AD / 4; ++q) {
                float4 a = s4[q];
                float4 b = d4[q];
                feat[4*q+0] = a.x + b.x;
                feat[4*q+1] = a.y + b.y;
                feat[4*q+2] = a.z + b.z;
                feat[4*q+3] = a.w + b.w;
            }
            const float energy = fmaf(benergy[e], we, bee);
            float logit = wb2;
#pragma unroll
            for (int j = 0; j < HID; ++j) {
                float s = fmaf(energy, W1[j*IN_DIM + 32], b1[j]);
#pragma unroll
                for (int i = 0; i < AD; ++i)
                    s = fmaf(feat[i], W1[j*IN_DIM + i], s);
                logit = fmaf(W2[j], fmaxf(s, 0.0f), logit);
            }
            sc[k] = sigmoidf_fast(logit);
        }
        out[t] = 0.5f * (sc[0] + sc[1]);
    }
}

extern "C" void kernel_launch(void* const* d_in, const int* in_sizes, int n_in,
                              void* d_out, int out_size, void* d_ws, size_t ws_size,
                              hipStream_t stream) {
    const float* emb     = (const float*)d_in[0];
    const float* benergy = (const float*)d_in[1];
    const float* We      = (const float*)d_in[2];
    const float* be      = (const float*)d_in[3];
    const float* W1      = (const float*)d_in[4];
    const float* b1      = (const float*)d_in[5];
    const float* W2      = (const float*)d_in[6];
    const float* b2      = (const float*)d_in[7];
    const int*   eidx    = (const int*)d_in[8];
    float* out = (float*)d_out;

    const int N    = in_sizes[0] / AD;
    const int E    = in_sizes[1];
    const int half = out_size;   // E/2

    const size_t need = (size_t)N * HID * sizeof(__half);
    if (ws_size >= need) {
        __half* hpre = (__half*)d_ws;
        const int blocks1 = (N + 255) / 256;
        atom_pre_kernel<<<blocks1, 256, 0, stream>>>(emb, W1, hpre, N);
        const int nt = (half + 1) >> 1;
        const int blocks2 = (nt + 255) / 256;
        edge_kernel<<<blocks2, 256, 0, stream>>>(hpre, eidx, benergy,
                                                 W1, b1, W2, b2, We, be,
                                                 out, E, half);
    } else {
        const int blocks = imin_host((half + 255) / 256, 2048);
        fused_kernel<<<blocks, 256, 0, stream>>>(emb, eidx, benergy,
                                                 W1, b1, W2, b2, We, be,
                                                 out, E, half);
    }
}

// Round 5
// 160.248 us; speedup vs baseline: 1.0303x; 1.0303x over previous
//
#include <hip/hip_runtime.h>
#include <hip/hip_fp16.h>

#define AD 32
#define HID 16
#define IN_DIM 33

typedef float f32x4 __attribute__((ext_vector_type(4)));

union VU {
    f32x4 v;
    __half2 h[4];
};

static inline int imin_host(int a, int b) { return a < b ? a : b; }

__device__ __forceinline__ float sigmoidf_fast(float x) {
    return 1.0f / (1.0f + __expf(-x));
}

// Phase 1: hpre[a][j] = sum_i emb[a][i] * W1[j][i]  (cols 0..31), stored fp16.
// Plain cached loads (NT loads broke line reuse in round 2); NT stores OK.
__global__ __launch_bounds__(256) void atom_pre_kernel(
    const float* __restrict__ emb,   // [N,32]
    const float* __restrict__ W1,    // [16,33] row-major (out,in)
    __half* __restrict__ hpre,       // [N,16] fp16
    int N)
{
    int a = blockIdx.x * blockDim.x + threadIdx.x;
    if (a >= N) return;

    const f32x4* e4 = reinterpret_cast<const f32x4*>(emb + (size_t)a * AD);
    float x[AD];
#pragma unroll
    for (int q = 0; q < AD / 4; ++q) {
        f32x4 v = e4[q];
        x[4*q+0] = v.x; x[4*q+1] = v.y; x[4*q+2] = v.z; x[4*q+3] = v.w;
    }

    float s[HID];
#pragma unroll
    for (int j = 0; j < HID; ++j) {
        float acc = 0.0f;
#pragma unroll
        for (int i = 0; i < AD; ++i)
            acc = fmaf(x[i], W1[j*IN_DIM + i], acc);
        s[j] = acc;
    }

    VU a0, a1;
#pragma unroll
    for (int q = 0; q < 4; ++q) a0.h[q] = __floats2half2_rn(s[2*q],   s[2*q+1]);
#pragma unroll
    for (int q = 0; q < 4; ++q) a1.h[q] = __floats2half2_rn(s[8+2*q], s[8+2*q+1]);

    f32x4* o4 = reinterpret_cast<f32x4*>(hpre + (size_t)a * HID);
    __builtin_nontemporal_store(a0.v, &o4[0]);
    __builtin_nontemporal_store(a1.v, &o4[1]);
}

// Phase 2: one output per thread. Issue all gathers up-front, then compute.
// (Round-4 A/B: 2 outputs/thread did NOT help -> throughput-bound; keep 1.)
__global__ __launch_bounds__(256) void edge_kernel(
    const __half* __restrict__ hpre,   // [N,16] fp16
    const int* __restrict__ eidx,      // [2,E]
    const float* __restrict__ benergy, // [E]
    const float* __restrict__ W1,      // [16,33] (need col 32)
    const float* __restrict__ b1,      // [16]
    const float* __restrict__ W2,      // [16]
    const float* __restrict__ b2,      // [1]
    const float* __restrict__ We,      // [1]
    const float* __restrict__ be,      // [1]
    float* __restrict__ out,           // [half]
    int E, int half)
{
    // Wave-uniform weight loads -> scalarized into SGPRs.
    float w1c[HID], bb1[HID], w2[HID];
#pragma unroll
    for (int j = 0; j < HID; ++j) {
        w1c[j] = W1[j*IN_DIM + 32];
        bb1[j] = b1[j];
        w2[j]  = W2[j];
    }
    const float wb2 = b2[0];
    const float we  = We[0];
    const float bee = be[0];

    const int t = blockIdx.x * blockDim.x + threadIdx.x;
    if (t >= half) return;

    const int e0 = t;
    const int e1 = t + half;

    // Stream loads (nontemporal: single-use, keep L2 for the table).
    const int s0 = __builtin_nontemporal_load(&eidx[e0]);
    const int d0 = __builtin_nontemporal_load(&eidx[E + e0]);
    const int s1 = __builtin_nontemporal_load(&eidx[e1]);
    const int d1 = __builtin_nontemporal_load(&eidx[E + e1]);
    const float ben0 = __builtin_nontemporal_load(&benergy[e0]);
    const float ben1 = __builtin_nontemporal_load(&benergy[e1]);

    // 4 row gathers x 2 x 16B, all independent -> all in flight together.
    const f32x4* rs0 = reinterpret_cast<const f32x4*>(hpre + (size_t)s0 * HID);
    const f32x4* rd0 = reinterpret_cast<const f32x4*>(hpre + (size_t)d0 * HID);
    const f32x4* rs1 = reinterpret_cast<const f32x4*>(hpre + (size_t)s1 * HID);
    const f32x4* rd1 = reinterpret_cast<const f32x4*>(hpre + (size_t)d1 * HID);

    f32x4 g0 = rs0[0], g1 = rs0[1];
    f32x4 g2 = rd0[0], g3 = rd0[1];
    f32x4 g4 = rs1[0], g5 = rs1[1];
    f32x4 g6 = rd1[0], g7 = rd1[1];

    float en[2];
    en[0] = fmaf(ben0, we, bee);
    en[1] = fmaf(ben1, we, bee);

    float sc[2];
#pragma unroll
    for (int k = 0; k < 2; ++k) {
        VU us0, us1, ud0, ud1;
        if (k == 0) { us0.v = g0; us1.v = g1; ud0.v = g2; ud1.v = g3; }
        else        { us0.v = g4; us1.v = g5; ud0.v = g6; ud1.v = g7; }

        float logit = wb2;
#pragma unroll
        for (int q = 0; q < 4; ++q) {
            float2 sf = __half22float2(__hadd2(us0.h[q], ud0.h[q]));
            const int j = 2*q;
            float h0 = sf.x + fmaf(en[k], w1c[j],   bb1[j]);
            float h1 = sf.y + fmaf(en[k], w1c[j+1], bb1[j+1]);
            logit = fmaf(w2[j],   fmaxf(h0, 0.0f), logit);
            logit = fmaf(w2[j+1], fmaxf(h1, 0.0f), logit);
        }
#pragma unroll
        for (int q = 0; q < 4; ++q) {
            float2 sf = __half22float2(__hadd2(us1.h[q], ud1.h[q]));
            const int j = 8 + 2*q;
            float h0 = sf.x + fmaf(en[k], w1c[j],   bb1[j]);
            float h1 = sf.y + fmaf(en[k], w1c[j+1], bb1[j+1]);
            logit = fmaf(w2[j],   fmaxf(h0, 0.0f), logit);
            logit = fmaf(w2[j+1], fmaxf(h1, 0.0f), logit);
        }
        sc[k] = sigmoidf_fast(logit);
    }
    __builtin_nontemporal_store(0.5f * (sc[0] + sc[1]), &out[t]);
}

// Fallback (workspace too small): fully fused fp32, gathers raw embeddings.
__global__ __launch_bounds__(256) void fused_kernel(
    const float* __restrict__ emb,
    const int* __restrict__ eidx,
    const float* __restrict__ benergy,
    const float* __restrict__ W1, const float* __restrict__ b1,
    const float* __restrict__ W2, const float* __restrict__ b2,
    const float* __restrict__ We, const float* __restrict__ be,
    float* __restrict__ out, int E, int half)
{
    const float we  = We[0];
    const float bee = be[0];
    const float wb2 = b2[0];
    int stride = gridDim.x * blockDim.x;
    for (int t = blockIdx.x * blockDim.x + threadIdx.x; t < half; t += stride) {
        float sc[2];
#pragma unroll
        for (int k = 0; k < 2; ++k) {
            const int e = t + k * half;
            const int src = eidx[e];
            const int dst = eidx[E + e];
            const float4* s4 = reinterpret_cast<const float4*>(emb + (size_t)src * AD);
            const float4* d4 = reinterpret_cast<const float4*>(emb + (size_t)dst * AD);
            float feat[AD];
#pragma unroll
            for (int q = 0; q < AD / 4; ++q) {
                float4 a = s4[q];
                float4 b = d4[q];
                feat[4*q+0] = a.x + b.x;
                feat[4*q+1] = a.y + b.y;
                feat[4*q+2] = a.z + b.z;
                feat[4*q+3] = a.w + b.w;
            }
            const float energy = fmaf(benergy[e], we, bee);
            float logit = wb2;
#pragma unroll
            for (int j = 0; j < HID; ++j) {
                float s = fmaf(energy, W1[j*IN_DIM + 32], b1[j]);
#pragma unroll
                for (int i = 0; i < AD; ++i)
                    s = fmaf(feat[i], W1[j*IN_DIM + i], s);
                logit = fmaf(W2[j], fmaxf(s, 0.0f), logit);
            }
            sc[k] = sigmoidf_fast(logit);
        }
        out[t] = 0.5f * (sc[0] + sc[1]);
    }
}

extern "C" void kernel_launch(void* const* d_in, const int* in_sizes, int n_in,
                              void* d_out, int out_size, void* d_ws, size_t ws_size,
                              hipStream_t stream) {
    const float* emb     = (const float*)d_in[0];
    const float* benergy = (const float*)d_in[1];
    const float* We      = (const float*)d_in[2];
    const float* be      = (const float*)d_in[3];
    const float* W1      = (const float*)d_in[4];
    const float* b1      = (const float*)d_in[5];
    const float* W2      = (const float*)d_in[6];
    const float* b2      = (const float*)d_in[7];
    const int*   eidx    = (const int*)d_in[8];
    float* out = (float*)d_out;

    const int N    = in_sizes[0] / AD;
    const int E    = in_sizes[1];
    const int half = out_size;   // E/2

    const size_t need = (size_t)N * HID * sizeof(__half);
    if (ws_size >= need) {
        __half* hpre = (__half*)d_ws;
        const int blocks1 = (N + 255) / 256;
        atom_pre_kernel<<<blocks1, 256, 0, stream>>>(emb, W1, hpre, N);
        const int blocks2 = (half + 255) / 256;
        edge_kernel<<<blocks2, 256, 0, stream>>>(hpre, eidx, benergy,
                                                 W1, b1, W2, b2, We, be,
                                                 out, E, half);
    } else {
        const int blocks = imin_host((half + 255) / 256, 2048);
        fused_kernel<<<blocks, 256, 0, stream>>>(emb, eidx, benergy,
                                                 W1, b1, W2, b2, We, be,
                                                 out, E, half);
    }
}